// Round 13
// baseline (78.897 us; speedup 1.0000x reference)
//
#include <hip/hip_runtime.h>
#include <hip/hip_bf16.h>
#include <math.h>

#define B_ 16
#define C_ 256
#define H_ 64
#define W_ 64
#define KD_ 128
#define P_ 256
#define HW_ (H_ * W_)

typedef __bf16 bf16;
typedef float f32x4_t __attribute__((ext_vector_type(4)));
typedef float f32x16_t __attribute__((ext_vector_type(16)));
typedef unsigned char u8;

// ---- fp8 e4m3 pack helpers (v_cvt_pk_fp8_f32: 2 floats -> 2 bytes) --------
__device__ __forceinline__ unsigned cvt_pk_fp8_lo(float a, float b, unsigned old) {
#if __has_builtin(__builtin_amdgcn_cvt_pk_fp8_f32)
    return __builtin_amdgcn_cvt_pk_fp8_f32(a, b, old, false);
#else
    unsigned r = old;
    asm("v_cvt_pk_fp8_f32 %0, %1, %2" : "+v"(r) : "v"(a), "v"(b));
    return r;
#endif
}
__device__ __forceinline__ unsigned cvt_pk_fp8_hi(float a, float b, unsigned old) {
#if __has_builtin(__builtin_amdgcn_cvt_pk_fp8_f32)
    return __builtin_amdgcn_cvt_pk_fp8_f32(a, b, old, true);
#else
    unsigned r = old;
    asm("v_cvt_pk_fp8_f32 %0, %1, %2 op_sel:[0,0,1]" : "+v"(r) : "v"(a), "v"(b));
    return r;
#endif
}
__device__ __forceinline__ uint2 pack8_fp8(const float* f) {
    uint2 r;
    r.x = cvt_pk_fp8_hi(f[2], f[3], cvt_pk_fp8_lo(f[0], f[1], 0u));
    r.y = cvt_pk_fp8_hi(f[6], f[7], cvt_pk_fp8_lo(f[4], f[5], 0u));
    return r;
}
// fp8 e4m3 byte -> f32 (SEL = byte index in the u32)
template<int SEL>
__device__ __forceinline__ float fp8_to_f32(unsigned w) {
#if __has_builtin(__builtin_amdgcn_cvt_f32_fp8)
    return __builtin_amdgcn_cvt_f32_fp8(w, SEL);
#else
    float r;
    asm("v_cvt_f32_fp8 %0, %1" : "=v"(r) : "v"(w >> (SEL * 8)));
    return r;
#endif
}

// ---------------------------------------------------------------------------
// k_prep1: per-prototype K/V projections; K row-L2-normalized and scaled by
// 1/TEMP, written fp32 (packed by k_prep23). Verified rounds 0-12.
// ---------------------------------------------------------------------------
__global__ __launch_bounds__(128) void k_prep1(
    const float* __restrict__ m_feat,
    const float* __restrict__ k_w, const float* __restrict__ k_b,
    const float* __restrict__ v_w, const float* __restrict__ v_b,
    float* __restrict__ kn_f, float* __restrict__ v_f)
{
    const int p = blockIdx.x;
    const int j = threadIdx.x;
    __shared__ float msh[KD_];
    __shared__ float red[2];
    msh[j] = m_feat[p * KD_ + j];
    __syncthreads();

    float ka = k_b[j];
    float va = v_b[j];
#pragma unroll 4
    for (int d = 0; d < KD_; ++d) {
        const float m = msh[d];
        ka = fmaf(m, k_w[j * KD_ + d], ka);
        va = fmaf(m, v_w[j * KD_ + d], va);
    }
    float s = ka * ka;
#pragma unroll
    for (int o = 1; o < 64; o <<= 1) s += __shfl_xor(s, o);
    if ((j & 63) == 0) red[j >> 6] = s;
    __syncthreads();
    s = red[0] + red[1];
    const float inv = 1.0f / (0.07f * fmaxf(sqrtf(s), 1e-12f)); // fold 1/TEMP
    kn_f[p * KD_ + j] = ka * inv;
    v_f[p * KD_ + j] = va;
}

// ---------------------------------------------------------------------------
// k_prep23: merged prep2+prep3, packing for the 32x32x16 MFMA family.
// Verified rounds 4-12.
// ---------------------------------------------------------------------------
__global__ __launch_bounds__(256) void k_prep23(
    const float* __restrict__ o_w, const float* __restrict__ v_f,
    const float* __restrict__ q_w, const float* __restrict__ kn_f,
    u8* __restrict__ m28, u8* __restrict__ qw8, u8* __restrict__ kn8)
{
    if (blockIdx.x < 256) {
        const int c = blockIdx.x;
        const int p = threadIdx.x;
        __shared__ float osh[KD_];
        if (p < KD_) osh[p] = o_w[c * KD_ + p];
        __syncthreads();
        float acc = 0.f;
#pragma unroll 4
        for (int k = 0; k < KD_; ++k) acc = fmaf(osh[k], v_f[p * KD_ + k], acc);
        const int mt = c >> 5, r = c & 31;
        const int ks = p >> 4, sub = (p >> 3) & 1, jj = p & 7;
        const unsigned pk = cvt_pk_fp8_lo(acc * 16.0f, 0.f, 0u);
        m28[(((mt * 16 + ks) * 64) + sub * 32 + r) * 8 + jj] = (u8)(pk & 0xffu);
    } else {
        const int t = (blockIdx.x - 256) * 256 + threadIdx.x;  // 0..8191
        float f[8];
        if (t < 4096) {  // qw8: 128x256 -> 4 mt x 16 ks
            const int lane = t & 63, g = t >> 6, mt = g >> 4, ks = g & 15;
            const int row = mt * 32 + (lane & 31), k0 = ks * 16 + (lane >> 5) * 8;
            const float* src = q_w + row * C_ + k0;
#pragma unroll
            for (int j = 0; j < 8; ++j) f[j] = src[j] * 16.0f;
            ((uint2*)qw8)[t] = pack8_fp8(f);
        } else {         // kn8: 256x128 -> 8 mt x 8 ks
            const int u = t - 4096;
            const int lane = u & 63, g = u >> 6, mt = g >> 3, ks = g & 7;
            const int row = mt * 32 + (lane & 31), k0 = ks * 16 + (lane >> 5) * 8;
            const float* src = kn_f + row * KD_ + k0;
#pragma unroll
            for (int j = 0; j < 8; ++j) f[j] = src[j];
            ((uint2*)kn8)[u] = pack8_fp8(f);
        }
    }
}

// ---------------------------------------------------------------------------
// k_attn v24: 4-row blocks (256 pixels) -> stage reads are 1KB WAVE-
// CONTIGUOUS per instruction (each wave sweeps one full channel's 1KB).
// Session chunk-size law: 256B->2TB/s (r3), 512B->2TB/s (r8/r9), 8KB->6.5
// TB/s (xpose). Stage is ~30us of k_attn's 47 -> doubling effective BW is
// the last unexplored lever. 1024 threads, grid 256 = 1 block/CU = same
// 16 waves/CU as r8. All phase bodies = r8's verified code, reindexed:
//   GEMM-A: wave=(mtA=wid&3, np=wid>>2), 2 N-tiles (pixels np*64..+63).
//   GEMM-B/C: wave=(mt=wid>>1, half=wid&1), 4 N-tiles (pixels half*128..).
// LDS (151552B, 1 block/CU): [0,64K) tile -> qbuf[0,32K) after barrier B ->
// ebuf[0,64K) after barrier 2 (qbuf dead; r8's overlay timeline). [64K,128K)
// xs. [128K..) ss 4K | pmax 8K | sum 8K. Epilogue: r8 byte stores (r12
// proved write-amplification is free). C/D frag: col=lane&31,
// row=(reg&3)+8*(reg>>2)+4*(lane>>5) [m74/m101].
// ---------------------------------------------------------------------------
__global__ __launch_bounds__(1024, 4) void k_attn(
    const float* __restrict__ x,
    const float* __restrict__ q_b, const float* __restrict__ o_b,
    const u8* __restrict__ qw8, const u8* __restrict__ kn8,
    const u8* __restrict__ m28, u8* __restrict__ outf8)
{
    __shared__ __align__(16) char lds[151552];
    char* const xs = lds + 65536;                   // [64K,128K) xs fp8 [256px][256c]
    float* const ss_lds   = (float*)(lds + 131072); // [256][4]
    float* const pmax_lds = (float*)(lds + 135168); // [256][8]
    float* const sum_lds  = (float*)(lds + 143360); // [256][8]

    const int rq = blockIdx.x;       // row quad 0..15 (rows rq*4..+3)
    const int b = blockIdx.y;
    const int tid = threadIdx.x;     // 0..1023
    const int lane = tid & 63;
    const int wid = tid >> 6;        // 0..15
    const int l31 = lane & 31;
    const int kh  = lane >> 5;       // k-half within fragment
    const int mt = wid >> 1;         // GEMM-B/C M-tile 0..7
    const int half = wid & 1;        // pixel half 0..1

    // persistent kn fp8 A-frags for GEMM-B (16 VGPR); loads hide under staging
    long kna[8];
#pragma unroll
    for (int ks = 0; ks < 8; ++ks)
        kna[ks] = *(const long*)(kn8 + ((mt * 8 + ks) * 64 + lane) * 8);

    // ---- stage: x -> tile fp8 [256ch][256pix] at lds[0,64K).
    // Per wave-instruction: ONE channel, 64 lanes x 16B = 1KB contiguous.
    {
        const float* xb = x + (size_t)b * C_ * HW_ + rq * 256 + lane * 4;
#pragma unroll
        for (int it = 0; it < 16; ++it) {
            const int ch = it * 16 + wid;
            const f32x4_t v = *(const f32x4_t*)(xb + (size_t)ch * HW_);
            const unsigned w = cvt_pk_fp8_hi(v[2], v[3],
                               cvt_pk_fp8_lo(v[0], v[1], 0u));
            *(unsigned*)(lds + ch * 256 + lane * 4) = w;
        }
    }
    __syncthreads();  // barrier A: tile ready

    // ---- transpose tile -> xs [256pix][256c], swizzled (r8 pattern).
    {
        const int p  = tid & 255;
        const int cb = tid >> 8;     // 0..3: channels cb*64..+63
#pragma unroll
        for (int g = 0; g < 8; ++g) {
            const int c0 = cb * 64 + g * 8;
            union { u8 by[8]; uint2 u; } pk;
#pragma unroll
            for (int j = 0; j < 8; ++j)
                pk.by[j] = *(const u8*)(lds + (c0 + j) * 256 + p);
            *(uint2*)(xs + p * 256 + (c0 ^ ((p & 31) << 3))) = pk.u;
        }
    }
    __syncthreads();  // barrier B: xs ready; tile dead -> qbuf may use [0,32K)

    // ---- GEMM-A (fp8 32x32x16): q rows mtA*32..+31, pixels np*64..+63
    const int mtA = wid & 3, np = wid >> 2;   // np 0..3
    {
        f32x16_t qacc0, qacc1;
#pragma unroll
        for (int i = 0; i < 16; ++i) { qacc0[i] = 0.f; qacc1[i] = 0.f; }
#pragma unroll
        for (int ks = 0; ks < 16; ++ks) {
            const long a = *(const long*)(qw8 + ((mtA * 16 + ks) * 64 + lane) * 8);
            const int ko = (ks * 16 + kh * 8) ^ (l31 << 3);
            const long bx0 = *(const long*)(xs + (np * 64 + l31) * 256 + ko);
            const long bx1 = *(const long*)(xs + (np * 64 + 32 + l31) * 256 + ko);
            qacc0 = __builtin_amdgcn_mfma_f32_32x32x16_fp8_fp8(a, bx0, qacc0, 0, 0, 0);
            qacc1 = __builtin_amdgcn_mfma_f32_32x32x16_fp8_fp8(a, bx1, qacc1, 0, 0, 0);
        }
        // + 16*q_b; per-pixel sum-sq partial; write q fp8 (qbuf = lds[0,32K))
#pragma unroll
        for (int nt = 0; nt < 2; ++nt) {
            const int pix = np * 64 + nt * 32 + l31;
            float ssp = 0.f;
#pragma unroll
            for (int g = 0; g < 4; ++g) {
                const f32x4_t qbv = *(const f32x4_t*)(q_b + mtA * 32 + g * 8 + kh * 4);
#pragma unroll
                for (int i = 0; i < 4; ++i) {
                    float qv = (nt == 0) ? qacc0[g * 4 + i] : qacc1[g * 4 + i];
                    qv += 16.0f * qbv[i];
                    if (nt == 0) qacc0[g * 4 + i] = qv; else qacc1[g * 4 + i] = qv;
                    ssp = fmaf(qv, qv, ssp);
                }
            }
            ssp += __shfl_xor(ssp, 32);
            if (lane < 32) ss_lds[pix * 4 + mtA] = ssp;
#pragma unroll
            for (int g = 0; g < 4; ++g) {
                const float e0 = (nt == 0) ? qacc0[g * 4 + 0] : qacc1[g * 4 + 0];
                const float e1 = (nt == 0) ? qacc0[g * 4 + 1] : qacc1[g * 4 + 1];
                const float e2 = (nt == 0) ? qacc0[g * 4 + 2] : qacc1[g * 4 + 2];
                const float e3 = (nt == 0) ? qacc0[g * 4 + 3] : qacc1[g * 4 + 3];
                const unsigned qw_ = cvt_pk_fp8_hi(e2, e3, cvt_pk_fp8_lo(e0, e1, 0u));
                *(unsigned*)(lds + pix * 128 +
                             ((mtA * 32 + g * 8 + kh * 4) ^ ((l31 & 15) << 3))) = qw_;
            }
        }
    }
    __syncthreads();  // barrier 1: q + ss ready

    // ---- GEMM-B (fp8 32x32x16): kn rows mt*32..+31, pixels half*128..+127
    f32x16_t lacc0, lacc1, lacc2, lacc3;
#pragma unroll
    for (int i = 0; i < 16; ++i) { lacc0[i] = 0.f; lacc1[i] = 0.f; lacc2[i] = 0.f; lacc3[i] = 0.f; }
#pragma unroll
    for (int ks = 0; ks < 8; ++ks) {
        const int ko = (ks * 16 + kh * 8) ^ ((l31 & 15) << 3);
        const long bq0 = *(const long*)(lds + (half * 128 + 0 * 32 + l31) * 128 + ko);
        const long bq1 = *(const long*)(lds + (half * 128 + 1 * 32 + l31) * 128 + ko);
        const long bq2 = *(const long*)(lds + (half * 128 + 2 * 32 + l31) * 128 + ko);
        const long bq3 = *(const long*)(lds + (half * 128 + 3 * 32 + l31) * 128 + ko);
        lacc0 = __builtin_amdgcn_mfma_f32_32x32x16_fp8_fp8(kna[ks], bq0, lacc0, 0, 0, 0);
        lacc1 = __builtin_amdgcn_mfma_f32_32x32x16_fp8_fp8(kna[ks], bq1, lacc1, 0, 0, 0);
        lacc2 = __builtin_amdgcn_mfma_f32_32x32x16_fp8_fp8(kna[ks], bq2, lacc2, 0, 0, 0);
        lacc3 = __builtin_amdgcn_mfma_f32_32x32x16_fp8_fp8(kna[ks], bq3, lacc3, 0, 0, 0);
    }
    // per-pixel raw-logit max partial (this wave's 32 protos)
#pragma unroll
    for (int nt = 0; nt < 4; ++nt) {
        const int pix = half * 128 + nt * 32 + l31;
        float mx = -1e30f;
#pragma unroll
        for (int i = 0; i < 16; ++i) {
            const float lv = (nt == 0) ? lacc0[i] : (nt == 1) ? lacc1[i]
                           : (nt == 2) ? lacc2[i] : lacc3[i];
            mx = fmaxf(mx, lv);
        }
        mx = fmaxf(mx, __shfl_xor(mx, 32));
        if (lane < 32) pmax_lds[pix * 8 + mt] = mx;
    }
    __syncthreads();  // barrier 2: pmax ready; qbuf reads done -> ebuf may overlay

    // ---- softmax: qinv scale, max-subtracted, e x256 into fp8 (ebuf=lds[0,64K))
#pragma unroll
    for (int nt = 0; nt < 4; ++nt) {
        const int pix = half * 128 + nt * 32 + l31;
        const f32x4_t s4 = *(const f32x4_t*)(ss_lds + pix * 4);
        const float qinv = 1.0f / fmaxf(sqrtf(s4[0] + s4[1] + s4[2] + s4[3]), 1e-12f);
        const f32x4_t ma = *(const f32x4_t*)(pmax_lds + pix * 8);
        const f32x4_t mb = *(const f32x4_t*)(pmax_lds + pix * 8 + 4);
        const float cof = 5.545177444479562f -
                          fmaxf(fmaxf(fmaxf(ma[0], ma[1]), fmaxf(ma[2], ma[3])),
                                fmaxf(fmaxf(mb[0], mb[1]), fmaxf(mb[2], mb[3]))) * qinv;
        float sm = 0.f;
#pragma unroll
        for (int g = 0; g < 4; ++g) {
            float e[4];
#pragma unroll
            for (int i = 0; i < 4; ++i) {
                const float lv = (nt == 0) ? lacc0[g * 4 + i] : (nt == 1) ? lacc1[g * 4 + i]
                               : (nt == 2) ? lacc2[g * 4 + i] : lacc3[g * 4 + i];
                e[i] = __expf(fmaf(lv, qinv, cof));
                sm += e[i];
            }
            const unsigned ew = cvt_pk_fp8_hi(e[2], e[3],
                                cvt_pk_fp8_lo(e[0], e[1], 0u));
            const int p0 = mt * 32 + g * 8 + kh * 4;
            *(unsigned*)(lds + pix * 256 + (p0 ^ (l31 << 3))) = ew;
        }
        sm += __shfl_xor(sm, 32);
        if (lane < 32) sum_lds[pix * 8 + mt] = sm;
    }
    __syncthreads();  // barrier 3: e + sum ready

    // ---- GEMM-C (fp8 32x32x16): out channels mt*32..+31, pixels half*128..
    f32x16_t oacc0, oacc1, oacc2, oacc3;
#pragma unroll
    for (int i = 0; i < 16; ++i) { oacc0[i] = 0.f; oacc1[i] = 0.f; oacc2[i] = 0.f; oacc3[i] = 0.f; }
#pragma unroll
    for (int ks = 0; ks < 16; ++ks) {
        const long a = *(const long*)(m28 + ((mt * 16 + ks) * 64 + lane) * 8);
        const int ko = ks * 16 + kh * 8;
        const long be0 = *(const long*)(lds + (half * 128 + 0 * 32 + l31) * 256 + (ko ^ (l31 << 3)));
        const long be1 = *(const long*)(lds + (half * 128 + 1 * 32 + l31) * 256 + (ko ^ (l31 << 3)));
        const long be2 = *(const long*)(lds + (half * 128 + 2 * 32 + l31) * 256 + (ko ^ (l31 << 3)));
        const long be3 = *(const long*)(lds + (half * 128 + 3 * 32 + l31) * 256 + (ko ^ (l31 << 3)));
        oacc0 = __builtin_amdgcn_mfma_f32_32x32x16_fp8_fp8(a, be0, oacc0, 0, 0, 0);
        oacc1 = __builtin_amdgcn_mfma_f32_32x32x16_fp8_fp8(a, be1, oacc1, 0, 0, 0);
        oacc2 = __builtin_amdgcn_mfma_f32_32x32x16_fp8_fp8(a, be2, oacc2, 0, 0, 0);
        oacc3 = __builtin_amdgcn_mfma_f32_32x32x16_fp8_fp8(a, be3, oacc3, 0, 0, 0);
    }
    // epilogue: out16 = oacc/S + 16*o_b -> fp8 bytes (r8 pattern; block covers
    // pixels rq*256..+255 = two full 128B lines per channel).
    {
        u8* const obase = outf8 + (size_t)b * C_ * HW_ + rq * 256;
        f32x4_t obv16[4];
#pragma unroll
        for (int g = 0; g < 4; ++g) {
            const f32x4_t t = *(const f32x4_t*)(o_b + mt * 32 + g * 8 + kh * 4);
            obv16[g] = t * 16.0f;
        }
#pragma unroll
        for (int nt = 0; nt < 4; ++nt) {
            const int p = half * 128 + nt * 32 + l31;
            const f32x4_t sa = *(const f32x4_t*)(sum_lds + p * 8);
            const f32x4_t sb = *(const f32x4_t*)(sum_lds + p * 8 + 4);
            const float rs = 1.0f / ((sa[0] + sa[1] + sa[2] + sa[3]) +
                                     (sb[0] + sb[1] + sb[2] + sb[3]));
            u8* const op = obase + p;
#pragma unroll
            for (int g = 0; g < 4; ++g) {
                float o[4];
#pragma unroll
                for (int i = 0; i < 4; ++i) {
                    const float av = (nt == 0) ? oacc0[g * 4 + i] : (nt == 1) ? oacc1[g * 4 + i]
                                   : (nt == 2) ? oacc2[g * 4 + i] : oacc3[g * 4 + i];
                    o[i] = fmaf(av, rs, obv16[g][i]);
                }
                const unsigned u01 = cvt_pk_fp8_lo(o[0], o[1], 0u);
                const unsigned u23 = cvt_pk_fp8_lo(o[2], o[3], 0u);
                const int c = mt * 32 + g * 8 + kh * 4;
                op[(size_t)(c + 0) * HW_] = (u8)(u01 & 0xff);
                op[(size_t)(c + 1) * HW_] = (u8)((u01 >> 8) & 0xff);
                op[(size_t)(c + 2) * HW_] = (u8)(u23 & 0xff);
                op[(size_t)(c + 3) * HW_] = (u8)((u23 >> 8) & 0xff);
            }
        }
    }
}

// ---------------------------------------------------------------------------
// k_post v2.1 (verified rounds 6/8/9/10/11/12): depthwise 3x3 + BN1 + fast
// GELU, add, residual + gamma, BN2. fp8 outf8 in, quad-ILP. Unchanged.
// ---------------------------------------------------------------------------
__global__ __launch_bounds__(256, 4) void k_post(
    const float* __restrict__ x, const u8* __restrict__ outf8,
    const float* __restrict__ dw_w,
    const float* __restrict__ bn1_w, const float* __restrict__ bn1_b,
    const float* __restrict__ bn2_w, const float* __restrict__ bn2_b,
    const float* __restrict__ gamma, float* __restrict__ y)
{
    __shared__ __align__(16) u8 os8[64 + HW_ + 64];  // row -1 | 64 rows | row 64
    u8* const os = os8 + 64;
    const int bc = blockIdx.x;
    const int c = bc & (C_ - 1);
    const int tid = threadIdx.x;

    // stage: zeros in halo rows, data rows via uint4
    if (tid < 4)       *(uint4*)&os8[tid * 16] = make_uint4(0, 0, 0, 0);
    else if (tid < 8)  *(uint4*)&os8[64 + HW_ + (tid - 4) * 16] = make_uint4(0, 0, 0, 0);
    *(uint4*)&os[tid * 16] = *(const uint4*)(outf8 + (size_t)bc * HW_ + tid * 16);

    const float cbn = 0.99999500003750f;
    const float s1 = bn1_w[c] * cbn, b1 = bn1_b[c];
    const float s2 = bn2_w[c] * cbn, b2 = bn2_b[c];
    const float g = gamma[c];
    const float gc = g * 0.0625f;            // center stored x16
    float kw[9];
#pragma unroll
    for (int j = 0; j < 9; ++j) kw[j] = dw_w[c * 9 + j] * 0.0625f;  // fold /16

    __syncthreads();

    const int q = tid & 15;          // 4-pixel quad
    const int c4 = q * 4;
    const int r0 = tid >> 4;         // base row 0..15
    const float* xc = x + (size_t)bc * HW_;
    float* yc = y + (size_t)bc * HW_;

#pragma unroll
    for (int k = 0; k < 4; ++k) {
        const int r = r0 + k * 16;
        const f32x4_t x4 = *(const f32x4_t*)(xc + r * 64 + c4);
        // stencil rows in os8 coords: row r-1 at os8[r*64], row r at
        // os8[(r+1)*64], row r+1 at os8[(r+2)*64].
        float vt[6], vm[6], vb[6];
        {
            const int rbt = r * 64, rbm = rbt + 64, rbb = rbt + 128;
            const unsigned uCt = *(const unsigned*)&os8[rbt + c4];
            const unsigned uCm = *(const unsigned*)&os8[rbm + c4];
            const unsigned uCb = *(const unsigned*)&os8[rbb + c4];
            vt[1] = fp8_to_f32<0>(uCt); vt[2] = fp8_to_f32<1>(uCt);
            vt[3] = fp8_to_f32<2>(uCt); vt[4] = fp8_to_f32<3>(uCt);
            vm[1] = fp8_to_f32<0>(uCm); vm[2] = fp8_to_f32<1>(uCm);
            vm[3] = fp8_to_f32<2>(uCm); vm[4] = fp8_to_f32<3>(uCm);
            vb[1] = fp8_to_f32<0>(uCb); vb[2] = fp8_to_f32<1>(uCb);
            vb[3] = fp8_to_f32<2>(uCb); vb[4] = fp8_to_f32<3>(uCb);
            if (q > 0) {
                vt[0] = fp8_to_f32<3>(*(const unsigned*)&os8[rbt + c4 - 4]);
                vm[0] = fp8_to_f32<3>(*(const unsigned*)&os8[rbm + c4 - 4]);
                vb[0] = fp8_to_f32<3>(*(const unsigned*)&os8[rbb + c4 - 4]);
            } else { vt[0] = vm[0] = vb[0] = 0.f; }
            if (q < 15) {
                vt[5] = fp8_to_f32<0>(*(const unsigned*)&os8[rbt + c4 + 4]);
                vm[5] = fp8_to_f32<0>(*(const unsigned*)&os8[rbm + c4 + 4]);
                vb[5] = fp8_to_f32<0>(*(const unsigned*)&os8[rbb + c4 + 4]);
            } else { vt[5] = vm[5] = vb[5] = 0.f; }
        }
        f32x4_t y4;
#pragma unroll
        for (int j = 0; j < 4; ++j) {
            float conv = kw[0] * vt[j];
            conv = fmaf(kw[1], vt[j + 1], conv);
            conv = fmaf(kw[2], vt[j + 2], conv);
            conv = fmaf(kw[3], vm[j], conv);
            conv = fmaf(kw[4], vm[j + 1], conv);
            conv = fmaf(kw[5], vm[j + 2], conv);
            conv = fmaf(kw[6], vb[j], conv);
            conv = fmaf(kw[7], vb[j + 1], conv);
            conv = fmaf(kw[8], vb[j + 2], conv);
            const float t = fmaf(conv, s1, b1);
            const float lg = t / (1.0f + __expf(-1.702f * t));
            y4[j] = fmaf(lg, g, fmaf(vm[j + 1], gc, x4[j])) * s2 + b2;
        }
        *(f32x4_t*)(yc + r * 64 + c4) = y4;
    }
}

// ---------------------------------------------------------------------------
extern "C" void kernel_launch(void* const* d_in, const int* in_sizes, int n_in,
                              void* d_out, int out_size, void* d_ws, size_t ws_size,
                              hipStream_t stream)
{
    const float* x     = (const float*)d_in[0];
    const float* m_f   = (const float*)d_in[1];
    const float* q_w   = (const float*)d_in[2];
    const float* q_b   = (const float*)d_in[3];
    const float* k_w   = (const float*)d_in[4];
    const float* k_b   = (const float*)d_in[5];
    const float* v_w   = (const float*)d_in[6];
    const float* v_b   = (const float*)d_in[7];
    const float* o_w   = (const float*)d_in[8];
    const float* o_b   = (const float*)d_in[9];
    const float* dw_w  = (const float*)d_in[10];
    const float* bn1_w = (const float*)d_in[11];
    const float* bn1_b = (const float*)d_in[12];
    const float* bn2_w = (const float*)d_in[13];
    const float* bn2_b = (const float*)d_in[14];
    const float* gamma = (const float*)d_in[15];

    char* ws = (char*)d_ws;
    u8*    qw8   = (u8*)(ws);                    // 32 KB fp8 packed 16x q_w
    u8*    kn8   = (u8*)(ws + (32 << 10));       // 32 KB fp8 packed kn
    u8*    m28   = (u8*)(ws + (64 << 10));       // 64 KB fp8 packed 16x M2
    u8*    outf8 = (u8*)(ws + (1 << 20));        // 16 MB o_proj output, fp8 x16
    // prep-only fp32 scratch beyond outf8 (disjoint; kernels stream-ordered):
    float* kn_f  = (float*)(ws + (18 << 20));               // 128 KB
    float* v_f   = (float*)(ws + (18 << 20) + (128 << 10)); // 128 KB

    k_prep1<<<dim3(P_), dim3(128), 0, stream>>>(m_f, k_w, k_b, v_w, v_b,
                                                kn_f, v_f);
    k_prep23<<<dim3(288), dim3(256), 0, stream>>>(o_w, v_f, q_w, kn_f,
                                                  m28, qw8, kn8);
    k_attn<<<dim3(16, B_), dim3(1024), 0, stream>>>(x, q_b, o_b, qw8, kn8,
                                                    m28, outf8);
    k_post<<<dim3(B_ * C_), dim3(256), 0, stream>>>(
        x, outf8, dw_w, bn1_w, bn1_b, bn2_w, bn2_b, gamma, (float*)d_out);
}

// Round 14
// 73.973 us; speedup vs baseline: 1.0666x; 1.0666x over previous
//
#include <hip/hip_runtime.h>
#include <hip/hip_bf16.h>
#include <math.h>

#define B_ 16
#define C_ 256
#define H_ 64
#define W_ 64
#define KD_ 128
#define P_ 256
#define HW_ (H_ * W_)

typedef __bf16 bf16;
typedef float f32x4_t __attribute__((ext_vector_type(4)));
typedef float f32x16_t __attribute__((ext_vector_type(16)));
typedef unsigned char u8;

// ---- fp8 e4m3 pack helpers (v_cvt_pk_fp8_f32: 2 floats -> 2 bytes) --------
__device__ __forceinline__ unsigned cvt_pk_fp8_lo(float a, float b, unsigned old) {
#if __has_builtin(__builtin_amdgcn_cvt_pk_fp8_f32)
    return __builtin_amdgcn_cvt_pk_fp8_f32(a, b, old, false);
#else
    unsigned r = old;
    asm("v_cvt_pk_fp8_f32 %0, %1, %2" : "+v"(r) : "v"(a), "v"(b));
    return r;
#endif
}
__device__ __forceinline__ unsigned cvt_pk_fp8_hi(float a, float b, unsigned old) {
#if __has_builtin(__builtin_amdgcn_cvt_pk_fp8_f32)
    return __builtin_amdgcn_cvt_pk_fp8_f32(a, b, old, true);
#else
    unsigned r = old;
    asm("v_cvt_pk_fp8_f32 %0, %1, %2 op_sel:[0,0,1]" : "+v"(r) : "v"(a), "v"(b));
    return r;
#endif
}
__device__ __forceinline__ uint2 pack8_fp8(const float* f) {
    uint2 r;
    r.x = cvt_pk_fp8_hi(f[2], f[3], cvt_pk_fp8_lo(f[0], f[1], 0u));
    r.y = cvt_pk_fp8_hi(f[6], f[7], cvt_pk_fp8_lo(f[4], f[5], 0u));
    return r;
}
// fp8 e4m3 byte -> f32 (SEL = byte index in the u32)
template<int SEL>
__device__ __forceinline__ float fp8_to_f32(unsigned w) {
#if __has_builtin(__builtin_amdgcn_cvt_f32_fp8)
    return __builtin_amdgcn_cvt_f32_fp8(w, SEL);
#else
    float r;
    asm("v_cvt_f32_fp8 %0, %1" : "=v"(r) : "v"(w >> (SEL * 8)));
    return r;
#endif
}

// ---------------------------------------------------------------------------
// k_prep1: per-prototype K/V projections; K row-L2-normalized and scaled by
// 1/TEMP, written fp32 (packed by k_prep23). Verified rounds 0-13.
// ---------------------------------------------------------------------------
__global__ __launch_bounds__(128) void k_prep1(
    const float* __restrict__ m_feat,
    const float* __restrict__ k_w, const float* __restrict__ k_b,
    const float* __restrict__ v_w, const float* __restrict__ v_b,
    float* __restrict__ kn_f, float* __restrict__ v_f)
{
    const int p = blockIdx.x;
    const int j = threadIdx.x;
    __shared__ float msh[KD_];
    __shared__ float red[2];
    msh[j] = m_feat[p * KD_ + j];
    __syncthreads();

    float ka = k_b[j];
    float va = v_b[j];
#pragma unroll 4
    for (int d = 0; d < KD_; ++d) {
        const float m = msh[d];
        ka = fmaf(m, k_w[j * KD_ + d], ka);
        va = fmaf(m, v_w[j * KD_ + d], va);
    }
    float s = ka * ka;
#pragma unroll
    for (int o = 1; o < 64; o <<= 1) s += __shfl_xor(s, o);
    if ((j & 63) == 0) red[j >> 6] = s;
    __syncthreads();
    s = red[0] + red[1];
    const float inv = 1.0f / (0.07f * fmaxf(sqrtf(s), 1e-12f)); // fold 1/TEMP
    kn_f[p * KD_ + j] = ka * inv;
    v_f[p * KD_ + j] = va;
}

// ---------------------------------------------------------------------------
// k_prep23: merged prep2+prep3, packing for the 32x32x16 MFMA family.
// Verified rounds 4-13.
// ---------------------------------------------------------------------------
__global__ __launch_bounds__(256) void k_prep23(
    const float* __restrict__ o_w, const float* __restrict__ v_f,
    const float* __restrict__ q_w, const float* __restrict__ kn_f,
    u8* __restrict__ m28, u8* __restrict__ qw8, u8* __restrict__ kn8)
{
    if (blockIdx.x < 256) {
        const int c = blockIdx.x;
        const int p = threadIdx.x;
        __shared__ float osh[KD_];
        if (p < KD_) osh[p] = o_w[c * KD_ + p];
        __syncthreads();
        float acc = 0.f;
#pragma unroll 4
        for (int k = 0; k < KD_; ++k) acc = fmaf(osh[k], v_f[p * KD_ + k], acc);
        const int mt = c >> 5, r = c & 31;
        const int ks = p >> 4, sub = (p >> 3) & 1, jj = p & 7;
        const unsigned pk = cvt_pk_fp8_lo(acc * 16.0f, 0.f, 0u);
        m28[(((mt * 16 + ks) * 64) + sub * 32 + r) * 8 + jj] = (u8)(pk & 0xffu);
    } else {
        const int t = (blockIdx.x - 256) * 256 + threadIdx.x;  // 0..8191
        float f[8];
        if (t < 4096) {  // qw8: 128x256 -> 4 mt x 16 ks
            const int lane = t & 63, g = t >> 6, mt = g >> 4, ks = g & 15;
            const int row = mt * 32 + (lane & 31), k0 = ks * 16 + (lane >> 5) * 8;
            const float* src = q_w + row * C_ + k0;
#pragma unroll
            for (int j = 0; j < 8; ++j) f[j] = src[j] * 16.0f;
            ((uint2*)qw8)[t] = pack8_fp8(f);
        } else {         // kn8: 256x128 -> 8 mt x 8 ks
            const int u = t - 4096;
            const int lane = u & 63, g = u >> 6, mt = g >> 3, ks = g & 7;
            const int row = mt * 32 + (lane & 31), k0 = ks * 16 + (lane >> 5) * 8;
            const float* src = kn_f + row * KD_ + k0;
#pragma unroll
            for (int j = 0; j < 8; ++j) f[j] = src[j];
            ((uint2*)kn8)[u] = pack8_fp8(f);
        }
    }
}

// ---------------------------------------------------------------------------
// k_attn v19 (round-8 source, 74.0 us -- session best; FINAL).
// 13 rounds of falsifiers: occupancy 16->32 waves (r3/r9 no effect), barriers
// 5->2 (r9/r10/r11 no effect/worse), write-amp eliminated (r12 no effect),
// pipelining (r2 regression), separate xpose pass (r4/r7/r10 3x loss),
// staging granularity 256B/512B/1KB/scatter (r3/r13/r9: this 512B fused
// variant is the optimum). Structure: stage (linear 512B-chunk reads ->
// tile[256c][128px]) -> transpose -> xs[128px][256c] swizzled -> GEMM-A ->
// qbuf (overlays tile) -> GEMM-B -> max-softmax -> ebuf (overlays qbuf) ->
// GEMM-C -> fp8 outf8 epilogue. 5 barriers, LDS 75776, 2 blocks/CU.
// Wave map: GEMM-A: (mtA=wid&3, nh=wid>>2) -> 2 N-tiles in row rp*2+nh.
//           GEMM-B/C: wave = M-tile wid, 4 N-tiles each.
// C/D frag: col=lane&31, row=(reg&3)+8*(reg>>2)+4*(lane>>5)  [m74/m101]
// ---------------------------------------------------------------------------
__global__ __launch_bounds__(512, 4) void k_attn(
    const float* __restrict__ x,
    const float* __restrict__ q_b, const float* __restrict__ o_b,
    const u8* __restrict__ qw8, const u8* __restrict__ kn8,
    const u8* __restrict__ m28, u8* __restrict__ outf8)
{
    __shared__ __align__(16) char lds[75776];
    char* const xs = lds + 32768;                   // [32K,64K) xs fp8 [128pix][256c]
    float* const ss_lds   = (float*)(lds + 65536);  // [128pix][4]
    float* const pmax_lds = (float*)(lds + 67584);  // [128pix][8]
    float* const sum_lds  = (float*)(lds + 71680);  // [128pix][8]

    const int rp = blockIdx.x;       // row pair 0..31
    const int b = blockIdx.y;
    const int tid = threadIdx.x;
    const int lane = tid & 63;
    const int wid = tid >> 6;        // 0..7
    const int l31 = lane & 31;
    const int kh  = lane >> 5;       // k-half within fragment

    // persistent kn fp8 A-frags for GEMM-B (16 VGPR); loads hide under staging
    long kna[8];
#pragma unroll
    for (int ks = 0; ks < 8; ++ks)
        kna[ks] = *(const long*)(kn8 + ((wid * 8 + ks) * 64 + lane) * 8);

    // ---- stage 1: x -> tile fp8 [256ch][128pix] at lds[0,32K).
    // Per wave-instruction: 2 channels x 512B contiguous (linear stream).
    {
        const int sub = tid & 31;    // pixel quad: pixels sub*4..+3
        const int ch0 = tid >> 5;    // 0..15
        const float* xb = x + (size_t)b * C_ * HW_ + rp * 128 + sub * 4;
#pragma unroll
        for (int it = 0; it < 16; ++it) {
            const int ch = it * 16 + ch0;
            const f32x4_t v = *(const f32x4_t*)(xb + (size_t)ch * HW_);
            const unsigned w = cvt_pk_fp8_hi(v[2], v[3],
                               cvt_pk_fp8_lo(v[0], v[1], 0u));
            *(unsigned*)(lds + ch * 128 + sub * 4) = w;
        }
    }
    __syncthreads();  // barrier A: tile ready

    // ---- stage 2: transpose tile -> xs [pix][256c], swizzled.
    {
        const int p  = tid & 127;
        const int cb = tid >> 7;     // 0..3: channels cb*64..+63
#pragma unroll
        for (int g = 0; g < 8; ++g) {
            const int c0 = cb * 64 + g * 8;
            union { u8 by[8]; uint2 u; } pk;
#pragma unroll
            for (int j = 0; j < 8; ++j)
                pk.by[j] = *(const u8*)(lds + (c0 + j) * 128 + p);
            *(uint2*)(xs + p * 256 + (c0 ^ ((p & 31) << 3))) = pk.u;
        }
    }
    __syncthreads();  // barrier B: xs ready; tile dead -> qbuf may use [0,16K)

    // ---- GEMM-A (fp8 32x32x16): q rows mtA*32..+31; 2 N-tiles in row rp*2+nh
    const int mtA = wid & 3, nh = wid >> 2;
    {
        f32x16_t qacc0, qacc1;
#pragma unroll
        for (int i = 0; i < 16; ++i) { qacc0[i] = 0.f; qacc1[i] = 0.f; }
#pragma unroll
        for (int ks = 0; ks < 16; ++ks) {
            const long a = *(const long*)(qw8 + ((mtA * 16 + ks) * 64 + lane) * 8);
            const int ko = (ks * 16 + kh * 8) ^ (l31 << 3);
            const long bx0 = *(const long*)(xs + (nh * 64 + l31) * 256 + ko);
            const long bx1 = *(const long*)(xs + (nh * 64 + 32 + l31) * 256 + ko);
            qacc0 = __builtin_amdgcn_mfma_f32_32x32x16_fp8_fp8(a, bx0, qacc0, 0, 0, 0);
            qacc1 = __builtin_amdgcn_mfma_f32_32x32x16_fp8_fp8(a, bx1, qacc1, 0, 0, 0);
        }
        // + 16*q_b; per-pixel sum-sq partial; write q fp8 (qbuf = lds[0,16K))
#pragma unroll
        for (int nt = 0; nt < 2; ++nt) {
            const int pix = nh * 64 + nt * 32 + l31;
            float ssp = 0.f;
#pragma unroll
            for (int g = 0; g < 4; ++g) {
                const f32x4_t qbv = *(const f32x4_t*)(q_b + mtA * 32 + g * 8 + kh * 4);
#pragma unroll
                for (int i = 0; i < 4; ++i) {
                    float qv = (nt == 0) ? qacc0[g * 4 + i] : qacc1[g * 4 + i];
                    qv += 16.0f * qbv[i];
                    if (nt == 0) qacc0[g * 4 + i] = qv; else qacc1[g * 4 + i] = qv;
                    ssp = fmaf(qv, qv, ssp);
                }
            }
            ssp += __shfl_xor(ssp, 32);
            if (lane < 32) ss_lds[pix * 4 + mtA] = ssp;
#pragma unroll
            for (int g = 0; g < 4; ++g) {
                const float e0 = (nt == 0) ? qacc0[g * 4 + 0] : qacc1[g * 4 + 0];
                const float e1 = (nt == 0) ? qacc0[g * 4 + 1] : qacc1[g * 4 + 1];
                const float e2 = (nt == 0) ? qacc0[g * 4 + 2] : qacc1[g * 4 + 2];
                const float e3 = (nt == 0) ? qacc0[g * 4 + 3] : qacc1[g * 4 + 3];
                const unsigned qw_ = cvt_pk_fp8_hi(e2, e3, cvt_pk_fp8_lo(e0, e1, 0u));
                *(unsigned*)(lds + pix * 128 +
                             ((mtA * 32 + g * 8 + kh * 4) ^ ((l31 & 15) << 3))) = qw_;
            }
        }
    }
    __syncthreads();  // barrier 1: q + ss ready

    // ---- GEMM-B (fp8 32x32x16): kn rows wid*32..+31, 128 pixels (4 N-tiles)
    f32x16_t lacc0, lacc1, lacc2, lacc3;
#pragma unroll
    for (int i = 0; i < 16; ++i) { lacc0[i] = 0.f; lacc1[i] = 0.f; lacc2[i] = 0.f; lacc3[i] = 0.f; }
#pragma unroll
    for (int ks = 0; ks < 8; ++ks) {
        const int ko = (ks * 16 + kh * 8) ^ ((l31 & 15) << 3);
        const long bq0 = *(const long*)(lds + (0 * 32 + l31) * 128 + ko);
        const long bq1 = *(const long*)(lds + (1 * 32 + l31) * 128 + ko);
        const long bq2 = *(const long*)(lds + (2 * 32 + l31) * 128 + ko);
        const long bq3 = *(const long*)(lds + (3 * 32 + l31) * 128 + ko);
        lacc0 = __builtin_amdgcn_mfma_f32_32x32x16_fp8_fp8(kna[ks], bq0, lacc0, 0, 0, 0);
        lacc1 = __builtin_amdgcn_mfma_f32_32x32x16_fp8_fp8(kna[ks], bq1, lacc1, 0, 0, 0);
        lacc2 = __builtin_amdgcn_mfma_f32_32x32x16_fp8_fp8(kna[ks], bq2, lacc2, 0, 0, 0);
        lacc3 = __builtin_amdgcn_mfma_f32_32x32x16_fp8_fp8(kna[ks], bq3, lacc3, 0, 0, 0);
    }
    // per-pixel raw-logit max partial (this wave's 32 protos)
#pragma unroll
    for (int nt = 0; nt < 4; ++nt) {
        const int pix = nt * 32 + l31;
        float mx = -1e30f;
#pragma unroll
        for (int i = 0; i < 16; ++i) {
            const float lv = (nt == 0) ? lacc0[i] : (nt == 1) ? lacc1[i]
                           : (nt == 2) ? lacc2[i] : lacc3[i];
            mx = fmaxf(mx, lv);
        }
        mx = fmaxf(mx, __shfl_xor(mx, 32));
        if (lane < 32) pmax_lds[pix * 8 + wid] = mx;
    }
    __syncthreads();  // barrier 2: pmax ready; all qbuf reads done -> ebuf may overlay

    // ---- softmax: qinv scale, max-subtracted, e x256 into fp8 (ebuf=lds[0,32K))
#pragma unroll
    for (int nt = 0; nt < 4; ++nt) {
        const int pix = nt * 32 + l31;
        const f32x4_t s4 = *(const f32x4_t*)(ss_lds + pix * 4);
        const float qinv = 1.0f / fmaxf(sqrtf(s4[0] + s4[1] + s4[2] + s4[3]), 1e-12f);
        const f32x4_t ma = *(const f32x4_t*)(pmax_lds + pix * 8);
        const f32x4_t mb = *(const f32x4_t*)(pmax_lds + pix * 8 + 4);
        const float cof = 5.545177444479562f -
                          fmaxf(fmaxf(fmaxf(ma[0], ma[1]), fmaxf(ma[2], ma[3])),
                                fmaxf(fmaxf(mb[0], mb[1]), fmaxf(mb[2], mb[3]))) * qinv;
        float sm = 0.f;
#pragma unroll
        for (int g = 0; g < 4; ++g) {
            float e[4];
#pragma unroll
            for (int i = 0; i < 4; ++i) {
                const float lv = (nt == 0) ? lacc0[g * 4 + i] : (nt == 1) ? lacc1[g * 4 + i]
                               : (nt == 2) ? lacc2[g * 4 + i] : lacc3[g * 4 + i];
                e[i] = __expf(fmaf(lv, qinv, cof));
                sm += e[i];
            }
            const unsigned ew = cvt_pk_fp8_hi(e[2], e[3],
                                cvt_pk_fp8_lo(e[0], e[1], 0u));
            const int p0 = wid * 32 + g * 8 + kh * 4;
            *(unsigned*)(lds + pix * 256 + (p0 ^ (l31 << 3))) = ew;
        }
        sm += __shfl_xor(sm, 32);
        if (lane < 32) sum_lds[pix * 8 + wid] = sm;
    }
    __syncthreads();  // barrier 3: e + sum ready

    // ---- GEMM-C (fp8 32x32x16): out channels wid*32..+31, 128 pixels
    f32x16_t oacc0, oacc1, oacc2, oacc3;
#pragma unroll
    for (int i = 0; i < 16; ++i) { oacc0[i] = 0.f; oacc1[i] = 0.f; oacc2[i] = 0.f; oacc3[i] = 0.f; }
#pragma unroll
    for (int ks = 0; ks < 16; ++ks) {
        const long a = *(const long*)(m28 + ((wid * 16 + ks) * 64 + lane) * 8);
        const int ko = ks * 16 + kh * 8;
        const long be0 = *(const long*)(lds + (0 * 32 + l31) * 256 + (ko ^ (l31 << 3)));
        const long be1 = *(const long*)(lds + (1 * 32 + l31) * 256 + (ko ^ (l31 << 3)));
        const long be2 = *(const long*)(lds + (2 * 32 + l31) * 256 + (ko ^ (l31 << 3)));
        const long be3 = *(const long*)(lds + (3 * 32 + l31) * 256 + (ko ^ (l31 << 3)));
        oacc0 = __builtin_amdgcn_mfma_f32_32x32x16_fp8_fp8(a, be0, oacc0, 0, 0, 0);
        oacc1 = __builtin_amdgcn_mfma_f32_32x32x16_fp8_fp8(a, be1, oacc1, 0, 0, 0);
        oacc2 = __builtin_amdgcn_mfma_f32_32x32x16_fp8_fp8(a, be2, oacc2, 0, 0, 0);
        oacc3 = __builtin_amdgcn_mfma_f32_32x32x16_fp8_fp8(a, be3, oacc3, 0, 0, 0);
    }
    // epilogue: out16 = oacc/S + 16*o_b -> fp8 bytes. Per channel the block
    // writes pixels 0..127 = one full 128B line at outf8[b][c][rp*128].
    {
        u8* const obase = outf8 + (size_t)b * C_ * HW_ + rp * 128;
        f32x4_t obv16[4];
#pragma unroll
        for (int g = 0; g < 4; ++g) {
            const f32x4_t t = *(const f32x4_t*)(o_b + wid * 32 + g * 8 + kh * 4);
            obv16[g] = t * 16.0f;
        }
#pragma unroll
        for (int nt = 0; nt < 4; ++nt) {
            const int p = nt * 32 + l31;
            const f32x4_t sa = *(const f32x4_t*)(sum_lds + p * 8);
            const f32x4_t sb = *(const f32x4_t*)(sum_lds + p * 8 + 4);
            const float rs = 1.0f / ((sa[0] + sa[1] + sa[2] + sa[3]) +
                                     (sb[0] + sb[1] + sb[2] + sb[3]));
            u8* const op = obase + p;
#pragma unroll
            for (int g = 0; g < 4; ++g) {
                float o[4];
#pragma unroll
                for (int i = 0; i < 4; ++i) {
                    const float av = (nt == 0) ? oacc0[g * 4 + i] : (nt == 1) ? oacc1[g * 4 + i]
                                   : (nt == 2) ? oacc2[g * 4 + i] : oacc3[g * 4 + i];
                    o[i] = fmaf(av, rs, obv16[g][i]);
                }
                const unsigned u01 = cvt_pk_fp8_lo(o[0], o[1], 0u);
                const unsigned u23 = cvt_pk_fp8_lo(o[2], o[3], 0u);
                const int c = wid * 32 + g * 8 + kh * 4;
                op[(size_t)(c + 0) * HW_] = (u8)(u01 & 0xff);
                op[(size_t)(c + 1) * HW_] = (u8)((u01 >> 8) & 0xff);
                op[(size_t)(c + 2) * HW_] = (u8)(u23 & 0xff);
                op[(size_t)(c + 3) * HW_] = (u8)((u23 >> 8) & 0xff);
            }
        }
    }
}

// ---------------------------------------------------------------------------
// k_post v2.1 (verified rounds 6-13): depthwise 3x3 + BN1 + fast GELU, add,
// residual + gamma, BN2. fp8 outf8 in, quad-ILP. Unchanged.
// ---------------------------------------------------------------------------
__global__ __launch_bounds__(256, 4) void k_post(
    const float* __restrict__ x, const u8* __restrict__ outf8,
    const float* __restrict__ dw_w,
    const float* __restrict__ bn1_w, const float* __restrict__ bn1_b,
    const float* __restrict__ bn2_w, const float* __restrict__ bn2_b,
    const float* __restrict__ gamma, float* __restrict__ y)
{
    __shared__ __align__(16) u8 os8[64 + HW_ + 64];  // row -1 | 64 rows | row 64
    u8* const os = os8 + 64;
    const int bc = blockIdx.x;
    const int c = bc & (C_ - 1);
    const int tid = threadIdx.x;

    // stage: zeros in halo rows, data rows via uint4
    if (tid < 4)       *(uint4*)&os8[tid * 16] = make_uint4(0, 0, 0, 0);
    else if (tid < 8)  *(uint4*)&os8[64 + HW_ + (tid - 4) * 16] = make_uint4(0, 0, 0, 0);
    *(uint4*)&os[tid * 16] = *(const uint4*)(outf8 + (size_t)bc * HW_ + tid * 16);

    const float cbn = 0.99999500003750f;
    const float s1 = bn1_w[c] * cbn, b1 = bn1_b[c];
    const float s2 = bn2_w[c] * cbn, b2 = bn2_b[c];
    const float g = gamma[c];
    const float gc = g * 0.0625f;            // center stored x16
    float kw[9];
#pragma unroll
    for (int j = 0; j < 9; ++j) kw[j] = dw_w[c * 9 + j] * 0.0625f;  // fold /16

    __syncthreads();

    const int q = tid & 15;          // 4-pixel quad
    const int c4 = q * 4;
    const int r0 = tid >> 4;         // base row 0..15
    const float* xc = x + (size_t)bc * HW_;
    float* yc = y + (size_t)bc * HW_;

#pragma unroll
    for (int k = 0; k < 4; ++k) {
        const int r = r0 + k * 16;
        const f32x4_t x4 = *(const f32x4_t*)(xc + r * 64 + c4);
        // stencil rows in os8 coords: row r-1 at os8[r*64], row r at
        // os8[(r+1)*64], row r+1 at os8[(r+2)*64].
        float vt[6], vm[6], vb[6];
        {
            const int rbt = r * 64, rbm = rbt + 64, rbb = rbt + 128;
            const unsigned uCt = *(const unsigned*)&os8[rbt + c4];
            const unsigned uCm = *(const unsigned*)&os8[rbm + c4];
            const unsigned uCb = *(const unsigned*)&os8[rbb + c4];
            vt[1] = fp8_to_f32<0>(uCt); vt[2] = fp8_to_f32<1>(uCt);
            vt[3] = fp8_to_f32<2>(uCt); vt[4] = fp8_to_f32<3>(uCt);
            vm[1] = fp8_to_f32<0>(uCm); vm[2] = fp8_to_f32<1>(uCm);
            vm[3] = fp8_to_f32<2>(uCm); vm[4] = fp8_to_f32<3>(uCm);
            vb[1] = fp8_to_f32<0>(uCb); vb[2] = fp8_to_f32<1>(uCb);
            vb[3] = fp8_to_f32<2>(uCb); vb[4] = fp8_to_f32<3>(uCb);
            if (q > 0) {
                vt[0] = fp8_to_f32<3>(*(const unsigned*)&os8[rbt + c4 - 4]);
                vm[0] = fp8_to_f32<3>(*(const unsigned*)&os8[rbm + c4 - 4]);
                vb[0] = fp8_to_f32<3>(*(const unsigned*)&os8[rbb + c4 - 4]);
            } else { vt[0] = vm[0] = vb[0] = 0.f; }
            if (q < 15) {
                vt[5] = fp8_to_f32<0>(*(const unsigned*)&os8[rbt + c4 + 4]);
                vm[5] = fp8_to_f32<0>(*(const unsigned*)&os8[rbm + c4 + 4]);
                vb[5] = fp8_to_f32<0>(*(const unsigned*)&os8[rbb + c4 + 4]);
            } else { vt[5] = vm[5] = vb[5] = 0.f; }
        }
        f32x4_t y4;
#pragma unroll
        for (int j = 0; j < 4; ++j) {
            float conv = kw[0] * vt[j];
            conv = fmaf(kw[1], vt[j + 1], conv);
            conv = fmaf(kw[2], vt[j + 2], conv);
            conv = fmaf(kw[3], vm[j], conv);
            conv = fmaf(kw[4], vm[j + 1], conv);
            conv = fmaf(kw[5], vm[j + 2], conv);
            conv = fmaf(kw[6], vb[j], conv);
            conv = fmaf(kw[7], vb[j + 1], conv);
            conv = fmaf(kw[8], vb[j + 2], conv);
            const float t = fmaf(conv, s1, b1);
            const float lg = t / (1.0f + __expf(-1.702f * t));
            y4[j] = fmaf(lg, g, fmaf(vm[j + 1], gc, x4[j])) * s2 + b2;
        }
        *(f32x4_t*)(yc + r * 64 + c4) = y4;
    }
}

// ---------------------------------------------------------------------------
extern "C" void kernel_launch(void* const* d_in, const int* in_sizes, int n_in,
                              void* d_out, int out_size, void* d_ws, size_t ws_size,
                              hipStream_t stream)
{
    const float* x     = (const float*)d_in[0];
    const float* m_f   = (const float*)d_in[1];
    const float* q_w   = (const float*)d_in[2];
    const float* q_b   = (const float*)d_in[3];
    const float* k_w   = (const float*)d_in[4];
    const float* k_b   = (const float*)d_in[5];
    const float* v_w   = (const float*)d_in[6];
    const float* v_b   = (const float*)d_in[7];
    const float* o_w   = (const float*)d_in[8];
    const float* o_b   = (const float*)d_in[9];
    const float* dw_w  = (const float*)d_in[10];
    const float* bn1_w = (const float*)d_in[11];
    const float* bn1_b = (const float*)d_in[12];
    const float* bn2_w = (const float*)d_in[13];
    const float* bn2_b = (const float*)d_in[14];
    const float* gamma = (const float*)d_in[15];

    char* ws = (char*)d_ws;
    u8*    qw8   = (u8*)(ws);                    // 32 KB fp8 packed 16x q_w
    u8*    kn8   = (u8*)(ws + (32 << 10));       // 32 KB fp8 packed kn
    u8*    m28   = (u8*)(ws + (64 << 10));       // 64 KB fp8 packed 16x M2
    u8*    outf8 = (u8*)(ws + (1 << 20));        // 16 MB o_proj output, fp8 x16
    // prep-only fp32 scratch beyond outf8 (disjoint; kernels stream-ordered):
    float* kn_f  = (float*)(ws + (18 << 20));               // 128 KB
    float* v_f   = (float*)(ws + (18 << 20) + (128 << 10)); // 128 KB

    k_prep1<<<dim3(P_), dim3(128), 0, stream>>>(m_f, k_w, k_b, v_w, v_b,
                                                kn_f, v_f);
    k_prep23<<<dim3(288), dim3(256), 0, stream>>>(o_w, v_f, q_w, kn_f,
                                                  m28, qw8, kn8);
    k_attn<<<dim3(H_ / 2, B_), dim3(512), 0, stream>>>(x, q_b, o_b, qw8, kn8,
                                                       m28, outf8);
    k_post<<<dim3(B_ * C_), dim3(256), 0, stream>>>(
        x, outf8, dw_w, bn1_w, bn1_b, bn2_w, bn2_b, gamma, (float*)d_out);
}